// Round 1
// baseline (303.264 us; speedup 1.0000x reference)
//
#include <hip/hip_runtime.h>
#include <hip/hip_bf16.h>
#include <stdint.h>

// ---------------------------------------------------------------------------
// CrossAttention: y = softmax((xWq^T)(ctxWk^T)^T * scale + mask) (ctxWv^T) Wo^T
// B=4 N=512 M=2048 C=1024 H=16 D=64.  All heavy math in bf16 MFMA, fp32 accum.
// ---------------------------------------------------------------------------

typedef __attribute__((ext_vector_type(4))) float f32x4;
typedef __attribute__((ext_vector_type(8))) __bf16 bf16x8;
typedef __attribute__((ext_vector_type(8))) unsigned short u16x8;

#define DEVI __device__ __forceinline__

DEVI f32x4 mfma16(u16x8 a, u16x8 b, f32x4 c) {
  return __builtin_amdgcn_mfma_f32_16x16x32_bf16(
      __builtin_bit_cast(bf16x8, a), __builtin_bit_cast(bf16x8, b), c, 0, 0, 0);
}

// round-to-nearest-even fp32 -> bf16
DEVI unsigned short f2bf(float f) {
  union { float f; unsigned int u; } x; x.f = f;
  unsigned int u = x.u;
  return (unsigned short)((u + 0x7fffu + ((u >> 16) & 1u)) >> 16);
}

// async global->LDS, 16 bytes per lane (global_load_lds_dwordx4)
DEVI void llds16(const void* g, void* l) {
  __builtin_amdgcn_global_load_lds(
      (const __attribute__((address_space(1))) void*)g,
      (__attribute__((address_space(3))) void*)l, 16, 0, 0);
}

// ---------------------------------------------------------------------------
__global__ __launch_bounds__(256)
void cast_kernel(const float* __restrict__ in, unsigned short* __restrict__ out, int n) {
  int idx = (blockIdx.x * 256 + threadIdx.x) * 4;
  if (idx >= n) return;
  const float4 v = *(const float4*)(in + idx);
  ushort4 o;
  o.x = f2bf(v.x); o.y = f2bf(v.y); o.z = f2bf(v.z); o.w = f2bf(v.w);
  *(ushort4*)(out + idx) = o;
}

// ---------------------------------------------------------------------------
// C = A[M,1024] @ W[1024,1024]^T (+bias). 128x128 tile, BK=64, 4 waves each 64x64.
// LDS layout XOR-swizzled at 16B-chunk granularity: slot s holds logical
// (m = s>>3, k8 = (s&7)^(m&7)); keeps global_load_lds (no padding) while giving
// 2-way-max bank aliasing on ds_read_b128 fragment loads.
// MODE 0: bf16 out, permuted to [B,H,S,64] (S = seq len, power of 2)
// MODE 1: fp32 out, row-major [M,1024]
template<int MODE, int S>
__global__ __launch_bounds__(256)
void gemm_bt(const unsigned short* __restrict__ A,
             const unsigned short* __restrict__ W,
             const float* __restrict__ bias,
             void* __restrict__ Cout) {
  constexpr int K = 1024;
  __shared__ __align__(16) unsigned short As[128 * 64];
  __shared__ __align__(16) unsigned short Bs[128 * 64];

  const int tid = threadIdx.x;
  const int wave = tid >> 6, lane = tid & 63;
  const int l15 = lane & 15, quad = lane >> 4;
  const int wm = wave & 1, wn = wave >> 1;
  const int bm = blockIdx.x * 128, bn = blockIdx.y * 128;

  f32x4 acc[4][4] = {};

  for (int k0 = 0; k0 < K; k0 += 64) {
    __syncthreads();
#pragma unroll
    for (int c = 0; c < 4; ++c) {
      int s = c * 256 + tid;
      int m = s >> 3;
      int k8 = (s & 7) ^ (m & 7);
      llds16(A + (bm + m) * K + k0 + k8 * 8, &As[s * 8]);
      llds16(W + (bn + m) * K + k0 + k8 * 8, &Bs[s * 8]);
    }
    __syncthreads();
#pragma unroll
    for (int ks = 0; ks < 2; ++ks) {
      u16x8 af[4], bf[4];
      const int k8 = ks * 4 + quad;
#pragma unroll
      for (int i = 0; i < 4; ++i) {
        int m = wm * 64 + i * 16 + l15;
        af[i] = *(const u16x8*)(&As[(m * 8 + (k8 ^ (m & 7))) * 8]);
        int n = wn * 64 + i * 16 + l15;
        bf[i] = *(const u16x8*)(&Bs[(n * 8 + (k8 ^ (n & 7))) * 8]);
      }
#pragma unroll
      for (int mi = 0; mi < 4; ++mi)
#pragma unroll
        for (int ni = 0; ni < 4; ++ni)
          acc[mi][ni] = mfma16(af[mi], bf[ni], acc[mi][ni]);
    }
  }

#pragma unroll
  for (int mi = 0; mi < 4; ++mi) {
#pragma unroll
    for (int ni = 0; ni < 4; ++ni) {
#pragma unroll
      for (int r = 0; r < 4; ++r) {
        int row = bm + wm * 64 + mi * 16 + quad * 4 + r;
        int col = bn + wn * 64 + ni * 16 + l15;
        float v = acc[mi][ni][r] + bias[col];
        if (MODE == 0) {
          int b = row / S, sl = row % S;
          int h = col >> 6, d = col & 63;
          ((unsigned short*)Cout)[(((b * 16 + h) * S) + sl) * 64 + d] = f2bf(v);
        } else {
          ((float*)Cout)[row * 1024 + col] = v;
        }
      }
    }
  }
}

// ---------------------------------------------------------------------------
// Flash-style attention. Grid (N/64, B*H). Block 256 = 4 waves; wave owns 16
// Q rows. Loops M in 64-key tiles: S=QK^T via MFMA, online softmax in the C/D
// layout (col=lane&15=key, row=quad*4+reg=q), P -> LDS round trip to A-operand
// layout, PV via MFMA with V transposed into LDS at stage time.
__global__ __launch_bounds__(256)
void attn_kernel(const unsigned short* __restrict__ Q,   // [B,H,512,64]
                 const unsigned short* __restrict__ Kp,  // [B,H,2048,64]
                 const unsigned short* __restrict__ Vp,  // [B,H,2048,64]
                 const int* __restrict__ mask,           // [B,2048]
                 unsigned short* __restrict__ O) {       // [B,512,1024]
  constexpr int Mlen = 2048;
  constexpr float SCALE = 0.125f;  // 64^-0.5
  __shared__ __align__(16) unsigned short k_lds[64 * 72];   // [key][d], +8 pad
  __shared__ __align__(16) unsigned short vt_lds[64 * 72];  // [d][key], +8 pad
  __shared__ __align__(16) unsigned short p_lds[4][16 * 72];

  const int tid = threadIdx.x;
  const int wave = tid >> 6, lane = tid & 63;
  const int l15 = lane & 15, quad = lane >> 4;
  const int bh = blockIdx.y;
  const int b = bh >> 4, h = bh & 15;
  const int q0 = blockIdx.x * 64 + wave * 16;

  const unsigned short* Qb = Q + (bh * 512 + q0) * 64;
  const unsigned short* Kb = Kp + bh * (Mlen * 64);
  const unsigned short* Vb = Vp + bh * (Mlen * 64);
  const int* maskb = mask + b * Mlen;

  u16x8 aq[2];
#pragma unroll
  for (int ks = 0; ks < 2; ++ks)
    aq[ks] = *(const u16x8*)(Qb + l15 * 64 + ks * 32 + quad * 8);

  f32x4 o_acc[4] = {};
  float m_r[4], l_r[4];
#pragma unroll
  for (int r = 0; r < 4; ++r) { m_r[r] = -1e30f; l_r[r] = 0.f; }

  for (int m0 = 0; m0 < Mlen; m0 += 64) {
    __syncthreads();
    // stage K tile [64key][64d] and V^T tile [64d][64key]
#pragma unroll
    for (int c = 0; c < 2; ++c) {
      int s = c * 256 + tid;
      int mm = s >> 3, k8 = s & 7;
      u16x8 kv = *(const u16x8*)(Kb + (m0 + mm) * 64 + k8 * 8);
      *(u16x8*)(&k_lds[mm * 72 + k8 * 8]) = kv;
      u16x8 vv = *(const u16x8*)(Vb + (m0 + mm) * 64 + k8 * 8);
#pragma unroll
      for (int j = 0; j < 8; ++j)
        vt_lds[(k8 * 8 + j) * 72 + mm] = vv[j];
    }
    __syncthreads();

    // S tile: 16 q-rows x 64 keys
    f32x4 sfr[4];
#pragma unroll
    for (int ns = 0; ns < 4; ++ns) {
      f32x4 sa = {0.f, 0.f, 0.f, 0.f};
#pragma unroll
      for (int ks = 0; ks < 2; ++ks) {
        u16x8 bf = *(const u16x8*)(&k_lds[(ns * 16 + l15) * 72 + ks * 32 + quad * 8]);
        sa = mfma16(aq[ks], bf, sa);
      }
      sfr[ns] = sa;
    }

    // scale + mask + tile row-max
    float pv[4][4], tmax[4];
#pragma unroll
    for (int r = 0; r < 4; ++r) tmax[r] = -1e30f;
#pragma unroll
    for (int ns = 0; ns < 4; ++ns) {
      float bv = maskb[m0 + ns * 16 + l15] ? 0.f : -1e30f;
#pragma unroll
      for (int r = 0; r < 4; ++r) {
        float sv = sfr[ns][r] * SCALE + bv;
        pv[ns][r] = sv;
        tmax[r] = fmaxf(tmax[r], sv);
      }
    }
#pragma unroll
    for (int off = 1; off < 16; off <<= 1)
#pragma unroll
      for (int r = 0; r < 4; ++r)
        tmax[r] = fmaxf(tmax[r], __shfl_xor(tmax[r], off, 64));

    float alpha[4];
#pragma unroll
    for (int r = 0; r < 4; ++r) {
      float mn = fmaxf(m_r[r], tmax[r]);
      alpha[r] = __expf(m_r[r] - mn);
      m_r[r] = mn;
    }
    float rsum[4] = {0.f, 0.f, 0.f, 0.f};
#pragma unroll
    for (int ns = 0; ns < 4; ++ns)
#pragma unroll
      for (int r = 0; r < 4; ++r) {
        float p = __expf(pv[ns][r] - m_r[r]);
        pv[ns][r] = p;
        rsum[r] += p;
      }
#pragma unroll
    for (int off = 1; off < 16; off <<= 1)
#pragma unroll
      for (int r = 0; r < 4; ++r)
        rsum[r] += __shfl_xor(rsum[r], off, 64);
#pragma unroll
    for (int r = 0; r < 4; ++r) l_r[r] = l_r[r] * alpha[r] + rsum[r];
#pragma unroll
    for (int nd = 0; nd < 4; ++nd)
#pragma unroll
      for (int r = 0; r < 4; ++r)
        o_acc[nd][r] *= alpha[r];

    // P (C-layout) -> LDS -> A-operand layout; per-wave region, in-wave
    // ordering guaranteed by lgkmcnt the compiler inserts.
#pragma unroll
    for (int ns = 0; ns < 4; ++ns)
#pragma unroll
      for (int r = 0; r < 4; ++r)
        p_lds[wave][(quad * 4 + r) * 72 + ns * 16 + l15] = f2bf(pv[ns][r]);

#pragma unroll
    for (int ks = 0; ks < 2; ++ks) {
      u16x8 af = *(const u16x8*)(&p_lds[wave][l15 * 72 + ks * 32 + quad * 8]);
#pragma unroll
      for (int nd = 0; nd < 4; ++nd) {
        u16x8 bf = *(const u16x8*)(&vt_lds[(nd * 16 + l15) * 72 + ks * 32 + quad * 8]);
        o_acc[nd] = mfma16(af, bf, o_acc[nd]);
      }
    }
  }

#pragma unroll
  for (int nd = 0; nd < 4; ++nd)
#pragma unroll
    for (int r = 0; r < 4; ++r) {
      int qrow = q0 + quad * 4 + r;
      int d = nd * 16 + l15;
      O[(b * 512 + qrow) * 1024 + h * 64 + d] = f2bf(o_acc[nd][r] / l_r[r]);
    }
}

// ---------------------------------------------------------------------------
extern "C" void kernel_launch(void* const* d_in, const int* in_sizes, int n_in,
                              void* d_out, int out_size, void* d_ws, size_t ws_size,
                              hipStream_t stream) {
  const float* x   = (const float*)d_in[0];
  const float* ctx = (const float*)d_in[1];
  const int* mask  = (const int*)d_in[2];
  const float* Wq  = (const float*)d_in[3];
  const float* bq  = (const float*)d_in[4];
  const float* Wk  = (const float*)d_in[5];
  const float* bk  = (const float*)d_in[6];
  const float* Wv  = (const float*)d_in[7];
  const float* bv  = (const float*)d_in[8];
  const float* Wo  = (const float*)d_in[9];
  const float* bo  = (const float*)d_in[10];

  char* ws = (char*)d_ws;
  unsigned short* xb  = (unsigned short*)(ws + (size_t)(0)  * (1 << 20));
  unsigned short* cb  = (unsigned short*)(ws + (size_t)(4)  * (1 << 20));
  unsigned short* wqb = (unsigned short*)(ws + (size_t)(20) * (1 << 20));
  unsigned short* wkb = (unsigned short*)(ws + (size_t)(22) * (1 << 20));
  unsigned short* wvb = (unsigned short*)(ws + (size_t)(24) * (1 << 20));
  unsigned short* wob = (unsigned short*)(ws + (size_t)(26) * (1 << 20));
  unsigned short* qh  = (unsigned short*)(ws + (size_t)(28) * (1 << 20));
  unsigned short* kh  = (unsigned short*)(ws + (size_t)(32) * (1 << 20));
  unsigned short* vh  = (unsigned short*)(ws + (size_t)(48) * (1 << 20));
  unsigned short* ah  = (unsigned short*)(ws + (size_t)(64) * (1 << 20));

  const int nX = 4 * 512 * 1024, nC = 4 * 2048 * 1024, nW = 1024 * 1024;
  cast_kernel<<<nX / 1024, 256, 0, stream>>>(x, xb, nX);
  cast_kernel<<<nC / 1024, 256, 0, stream>>>(ctx, cb, nC);
  cast_kernel<<<nW / 1024, 256, 0, stream>>>(Wq, wqb, nW);
  cast_kernel<<<nW / 1024, 256, 0, stream>>>(Wk, wkb, nW);
  cast_kernel<<<nW / 1024, 256, 0, stream>>>(Wv, wvb, nW);
  cast_kernel<<<nW / 1024, 256, 0, stream>>>(Wo, wob, nW);

  gemm_bt<0, 512><<<dim3(16, 8), 256, 0, stream>>>(xb, wqb, bq, (void*)qh);
  gemm_bt<0, 2048><<<dim3(64, 8), 256, 0, stream>>>(cb, wkb, bk, (void*)kh);
  gemm_bt<0, 2048><<<dim3(64, 8), 256, 0, stream>>>(cb, wvb, bv, (void*)vh);

  attn_kernel<<<dim3(8, 64), 256, 0, stream>>>(qh, kh, vh, mask, ah);

  gemm_bt<1, 512><<<dim3(16, 8), 256, 0, stream>>>(ah, wob, bo, d_out);
}

// Round 2
// 246.785 us; speedup vs baseline: 1.2289x; 1.2289x over previous
//
#include <hip/hip_runtime.h>
#include <hip/hip_bf16.h>
#include <stdint.h>

// ---------------------------------------------------------------------------
// CrossAttention B=4 N=512 M=2048 C=1024 H=16 D=64, bf16 MFMA fp32 accum.
// R2 design: split-K flash attention (waves own key stripes, no inner barriers,
// K/V frags loaded global->VGPR), S^T trick for per-lane softmax, exp2 domain,
// pre-transposed V, fused casts and fused QKV GEMM.
// ---------------------------------------------------------------------------

typedef __attribute__((ext_vector_type(4))) float f32x4;
typedef __attribute__((ext_vector_type(8))) __bf16 bf16x8;
typedef __attribute__((ext_vector_type(8))) unsigned short u16x8;

#define DEVI __device__ __forceinline__

// SCALE * log2(e): folded into Wq cast so QK^T scores land in log2 units.
#define QSC (0.125f * 1.44269504088896f)

DEVI f32x4 mfma16(u16x8 a, u16x8 b, f32x4 c) {
  return __builtin_amdgcn_mfma_f32_16x16x32_bf16(
      __builtin_bit_cast(bf16x8, a), __builtin_bit_cast(bf16x8, b), c, 0, 0, 0);
}

// round-to-nearest-even fp32 -> bf16
DEVI unsigned short f2bf(float f) {
  union { float f; unsigned int u; } x; x.f = f;
  unsigned int u = x.u;
  return (unsigned short)((u + 0x7fffu + ((u >> 16) & 1u)) >> 16);
}

DEVI float exp2_fast(float x) {
#if __has_builtin(__builtin_amdgcn_exp2f)
  return __builtin_amdgcn_exp2f(x);
#else
  return exp2f(x);
#endif
}

// async global->LDS, 16 bytes per lane (global_load_lds_dwordx4)
DEVI void llds16(const void* g, void* l) {
  __builtin_amdgcn_global_load_lds(
      (const __attribute__((address_space(1))) void*)g,
      (__attribute__((address_space(3))) void*)l, 16, 0, 0);
}

// ---------------------------------------------------------------------------
// One kernel casts all six fp32 inputs to bf16. Wq gets QSC folded in.
// Segments (blocks of 1024 elems): x 2048, ctx 8192, wq/wk/wv/wo 1024 each.
__global__ __launch_bounds__(256)
void cast_fused(const float* __restrict__ x, const float* __restrict__ ctx,
                const float* __restrict__ wq, const float* __restrict__ wk,
                const float* __restrict__ wv, const float* __restrict__ wo,
                unsigned short* __restrict__ xb, unsigned short* __restrict__ cb,
                unsigned short* __restrict__ wqb, unsigned short* __restrict__ wkb,
                unsigned short* __restrict__ wvb, unsigned short* __restrict__ wob) {
  int bid = blockIdx.x;
  const float* src; unsigned short* dst; float scale = 1.f;
  if (bid < 2048)        { src = x;   dst = xb; }
  else if (bid < 10240)  { src = ctx; dst = cb;  bid -= 2048; }
  else if (bid < 11264)  { src = wq;  dst = wqb; bid -= 10240; scale = QSC; }
  else if (bid < 12288)  { src = wk;  dst = wkb; bid -= 11264; }
  else if (bid < 13312)  { src = wv;  dst = wvb; bid -= 12288; }
  else                   { src = wo;  dst = wob; bid -= 13312; }
  int idx = (bid * 256 + threadIdx.x) * 4;
  const float4 v = *(const float4*)(src + idx);
  ushort4 o;
  o.x = f2bf(v.x * scale); o.y = f2bf(v.y * scale);
  o.z = f2bf(v.z * scale); o.w = f2bf(v.w * scale);
  *(ushort4*)(dst + idx) = o;
}

// ---------------------------------------------------------------------------
// GEMM body: C = A[.,1024] @ W[1024,1024]^T + bias*bscale. 128x128 tile, BK=64.
// MODE 0: bf16 out permuted to [B,H,S,64], S = 1<<logS. MODE 1: fp32 row-major.
template<int MODE>
DEVI void gemm_body(const unsigned short* __restrict__ A,
                    const unsigned short* __restrict__ W,
                    const float* __restrict__ bias,
                    void* __restrict__ Cout,
                    int bm, int bn, int logS, float bscale) {
  constexpr int K = 1024;
  __shared__ __align__(16) unsigned short As[128 * 64];
  __shared__ __align__(16) unsigned short Bs[128 * 64];

  const int tid = threadIdx.x;
  const int wave = tid >> 6, lane = tid & 63;
  const int l15 = lane & 15, quad = lane >> 4;
  const int wm = wave & 1, wn = wave >> 1;

  f32x4 acc[4][4] = {};

  for (int k0 = 0; k0 < K; k0 += 64) {
    __syncthreads();
#pragma unroll
    for (int c = 0; c < 4; ++c) {
      int s = c * 256 + tid;
      int m = s >> 3;
      int k8 = (s & 7) ^ (m & 7);
      llds16(A + (size_t)(bm + m) * K + k0 + k8 * 8, &As[s * 8]);
      llds16(W + (size_t)(bn + m) * K + k0 + k8 * 8, &Bs[s * 8]);
    }
    __syncthreads();
#pragma unroll
    for (int ks = 0; ks < 2; ++ks) {
      u16x8 af[4], bf[4];
      const int k8 = ks * 4 + quad;
#pragma unroll
      for (int i = 0; i < 4; ++i) {
        int m = wm * 64 + i * 16 + l15;
        af[i] = *(const u16x8*)(&As[(m * 8 + (k8 ^ (m & 7))) * 8]);
        int n = wn * 64 + i * 16 + l15;
        bf[i] = *(const u16x8*)(&Bs[(n * 8 + (k8 ^ (n & 7))) * 8]);
      }
#pragma unroll
      for (int mi = 0; mi < 4; ++mi)
#pragma unroll
        for (int ni = 0; ni < 4; ++ni)
          acc[mi][ni] = mfma16(af[mi], bf[ni], acc[mi][ni]);
    }
  }

#pragma unroll
  for (int mi = 0; mi < 4; ++mi) {
#pragma unroll
    for (int ni = 0; ni < 4; ++ni) {
#pragma unroll
      for (int r = 0; r < 4; ++r) {
        int row = bm + wm * 64 + mi * 16 + quad * 4 + r;
        int col = bn + wn * 64 + ni * 16 + l15;
        float v = acc[mi][ni][r] + bias[col] * bscale;
        if (MODE == 0) {
          int S = 1 << logS;
          int b = row >> logS, sl = row & (S - 1);
          int h = col >> 6, d = col & 63;
          ((unsigned short*)Cout)[(((size_t)(b * 16 + h) * S) + sl) * 64 + d] = f2bf(v);
        } else {
          ((float*)Cout)[(size_t)row * 1024 + col] = v;
        }
      }
    }
  }
}

// Fused Q/K/V projection. Grid (64, 18).
// y in [0,8): K tiles; y in [8,16): V tiles; y in {16,17}: Q tiles.
__global__ __launch_bounds__(256)
void gemm_qkv(const unsigned short* __restrict__ xb,
              const unsigned short* __restrict__ cb,
              const unsigned short* __restrict__ wq,
              const unsigned short* __restrict__ wk,
              const unsigned short* __restrict__ wv,
              const float* __restrict__ bq, const float* __restrict__ bk,
              const float* __restrict__ bv,
              unsigned short* __restrict__ qh, unsigned short* __restrict__ kh,
              unsigned short* __restrict__ vh) {
  const int x = blockIdx.x, y = blockIdx.y;
  const unsigned short *A, *W; const float* bi; unsigned short* out;
  int bm, bn, logS; float bsc = 1.f;
  if (y < 8)        { A = cb; W = wk; bi = bk; out = kh; bm = x * 128; bn = y * 128; logS = 11; }
  else if (y < 16)  { A = cb; W = wv; bi = bv; out = vh; bm = x * 128; bn = (y - 8) * 128; logS = 11; }
  else { A = xb; W = wq; bi = bq; out = qh; logS = 9; bsc = QSC;
         bm = (x & 15) * 128; bn = (y - 16) * 512 + (x >> 4) * 128; }
  gemm_body<0>(A, W, bi, out, bm, bn, logS, bsc);
}

// Output projection: fp32 out. Grid (16, 8).
__global__ __launch_bounds__(256)
void gemm_o(const unsigned short* __restrict__ ah,
            const unsigned short* __restrict__ wo,
            const float* __restrict__ bo, float* __restrict__ out) {
  gemm_body<1>(ah, wo, bo, out, blockIdx.x * 128, blockIdx.y * 128, 0, 1.f);
}

// ---------------------------------------------------------------------------
// V transpose: vh [64bh][2048][64] -> vt [64bh][64][2048]. Grid (32, 64).
__global__ __launch_bounds__(256)
void transpose_v(const unsigned short* __restrict__ vh,
                 unsigned short* __restrict__ vt) {
  __shared__ __align__(16) unsigned short t[64 * 72];
  const int bh = blockIdx.y, m0 = blockIdx.x * 64;
  const int tid = threadIdx.x;
  const unsigned short* src = vh + ((size_t)bh * 2048 + m0) * 64;
#pragma unroll
  for (int c = 0; c < 2; ++c) {
    int s = c * 256 + tid;
    int key = s >> 3, ch = s & 7;
    *(u16x8*)&t[key * 72 + ch * 8] = *(const u16x8*)(src + key * 64 + ch * 8);
  }
  __syncthreads();
  unsigned short* dst = vt + (size_t)bh * (64 * 2048) + m0;
#pragma unroll
  for (int c = 0; c < 2; ++c) {
    int s = c * 256 + tid;
    int d = s >> 3, kc = s & 7;
    u16x8 o;
#pragma unroll
    for (int j = 0; j < 8; ++j) o[j] = t[(kc * 8 + j) * 72 + d];
    *(u16x8*)(dst + (size_t)d * 2048 + kc * 8) = o;
  }
}

// ---------------------------------------------------------------------------
// Split-K flash attention. Grid (64 bh, 8 qblk), block 256 = 4 waves.
// Wave w covers keys {w*64 + 256t} (8 tiles); all waves share the block's 64
// q rows. No barriers in the main loop. Combine at end via LDS.
// Scores arrive in log2 units (Wq pre-scaled by QSC).
__global__ __launch_bounds__(256, 2)
void attn_kernel(const unsigned short* __restrict__ Q,   // [64][512][64]
                 const unsigned short* __restrict__ K,   // [64][2048][64]
                 const unsigned short* __restrict__ Vt,  // [64][64][2048]
                 const int* __restrict__ mask,           // [4][2048]
                 unsigned short* __restrict__ O) {       // [4][512][1024]
  __shared__ float bias_lds[2048];
  __shared__ __align__(16) unsigned short p_lds[4][16 * 72];
  __shared__ float ml_lds[2][4][64];
  __shared__ __align__(16) float o_comb[64][68];

  const int tid = threadIdx.x;
  const int wave = tid >> 6, lane = tid & 63;
  const int l15 = lane & 15, quad = lane >> 4;
  const int bh = blockIdx.x, b = bh >> 4, h = bh & 15;
  const int q0 = blockIdx.y * 64;

  {  // mask -> additive bias (log2 units are irrelevant at -1e30)
    const int* mb = mask + b * 2048;
    for (int i = tid; i < 2048; i += 256)
      bias_lds[i] = mb[i] ? 0.f : -1e30f;
  }
  __syncthreads();

  const unsigned short* Qb = Q + ((size_t)bh * 512 + q0) * 64;
  const unsigned short* Kb = K + (size_t)bh * (2048 * 64);
  const unsigned short* Vb = Vt + (size_t)bh * (64 * 2048);

  // Q fragments: lane l15 = q row, elements = d. Held all kernel.
  u16x8 aq[4][2];
#pragma unroll
  for (int qg = 0; qg < 4; ++qg)
#pragma unroll
    for (int ks = 0; ks < 2; ++ks)
      aq[qg][ks] = *(const u16x8*)(Qb + (qg * 16 + l15) * 64 + ks * 32 + quad * 8);

  f32x4 o_acc[4][4] = {};
  float m_s[4], l_s[4];
#pragma unroll
  for (int qg = 0; qg < 4; ++qg) { m_s[qg] = -3e30f; l_s[qg] = 0.f; }

#pragma unroll 1
  for (int t = 0; t < 8; ++t) {
    const int kb = wave * 64 + t * 256;  // this wave's key-tile base

    // K frags (A-op: lane=key, elems=d) and V^T frags (B-op: lane=d, elems=key)
    u16x8 kf[2][4], vf[2][4];
#pragma unroll
    for (int ns = 0; ns < 4; ++ns)
#pragma unroll
      for (int ks = 0; ks < 2; ++ks)
        kf[ks][ns] = *(const u16x8*)(Kb + (size_t)(kb + ns * 16 + l15) * 64 + ks * 32 + quad * 8);
#pragma unroll
    for (int nd = 0; nd < 4; ++nd)
#pragma unroll
      for (int ks = 0; ks < 2; ++ks)
        vf[ks][nd] = *(const u16x8*)(Vb + (size_t)(nd * 16 + l15) * 2048 + kb + ks * 32 + quad * 8);
    f32x4 bfr[4];
#pragma unroll
    for (int ns = 0; ns < 4; ++ns)
      bfr[ns] = *(const f32x4*)&bias_lds[kb + ns * 16 + quad * 4];

#pragma unroll
    for (int qg = 0; qg < 4; ++qg) {
      // S^T tile: D[key = ns*16+quad*4+r][q = l15]
      f32x4 sfr[4];
#pragma unroll
      for (int ns = 0; ns < 4; ++ns) {
        f32x4 sa = {0.f, 0.f, 0.f, 0.f};
#pragma unroll
        for (int ks = 0; ks < 2; ++ks)
          sa = mfma16(kf[ks][ns], aq[qg][ks], sa);
        sfr[ns] = sa;
      }

      float s[4][4], tmax = -3e30f;
#pragma unroll
      for (int ns = 0; ns < 4; ++ns)
#pragma unroll
        for (int r = 0; r < 4; ++r) {
          s[ns][r] = sfr[ns][r] + bfr[ns][r];
          tmax = fmaxf(tmax, s[ns][r]);
        }
      tmax = fmaxf(tmax, __shfl_xor(tmax, 16, 64));
      tmax = fmaxf(tmax, __shfl_xor(tmax, 32, 64));

      const float mn = fmaxf(m_s[qg], tmax);
      const float alpha = exp2_fast(m_s[qg] - mn);
      m_s[qg] = mn;

      float rsum = 0.f;
#pragma unroll
      for (int ns = 0; ns < 4; ++ns) {
        unsigned int pr[4];
#pragma unroll
        for (int r = 0; r < 4; ++r) {
          float p = exp2_fast(s[ns][r] - mn);
          unsigned int u = __builtin_bit_cast(unsigned int, p) & 0xffff0000u;
          rsum += __builtin_bit_cast(float, u);  // sum the TRUNCATED p: consistent with PV
          pr[r] = u;
        }
        uint2 pw;
        pw.x = __builtin_amdgcn_perm(pr[1], pr[0], 0x07060302u);
        pw.y = __builtin_amdgcn_perm(pr[3], pr[2], 0x07060302u);
        *(uint2*)&p_lds[wave][l15 * 72 + ns * 16 + quad * 4] = pw;
      }
      rsum += __shfl_xor(rsum, 16, 64);
      rsum += __shfl_xor(rsum, 32, 64);
      l_s[qg] = l_s[qg] * alpha + rsum;

      // rescale O rows (row index q = qg*16 + quad*4 + r; alpha lives at lane q%16)
      float ar[4];
#pragma unroll
      for (int r = 0; r < 4; ++r) ar[r] = __shfl(alpha, quad * 4 + r, 64);
#pragma unroll
      for (int nd = 0; nd < 4; ++nd)
#pragma unroll
        for (int r = 0; r < 4; ++r) o_acc[qg][nd][r] *= ar[r];

      // PV: A = P (lane=q, elems=key) from p_lds; B = V^T frags
#pragma unroll
      for (int ks = 0; ks < 2; ++ks) {
        u16x8 pf = *(const u16x8*)&p_lds[wave][l15 * 72 + ks * 32 + quad * 8];
#pragma unroll
        for (int nd = 0; nd < 4; ++nd)
          o_acc[qg][nd] = mfma16(pf, vf[ks][nd], o_acc[qg][nd]);
      }
    }
  }

  // ---- combine the 4 waves' partial (m,l,o) ----
  if (quad == 0) {
#pragma unroll
    for (int qg = 0; qg < 4; ++qg) {
      ml_lds[0][wave][qg * 16 + l15] = m_s[qg];
      ml_lds[1][wave][qg * 16 + l15] = l_s[qg];
    }
  }
  __syncthreads();

  for (int w = 0; w < 4; ++w) {
    if (wave == w) {
#pragma unroll
      for (int qg = 0; qg < 4; ++qg) {
#pragma unroll
        for (int r = 0; r < 4; ++r) {
          const int q = qg * 16 + quad * 4 + r;
          float mstar = fmaxf(fmaxf(ml_lds[0][0][q], ml_lds[0][1][q]),
                              fmaxf(ml_lds[0][2][q], ml_lds[0][3][q]));
          float sc = exp2_fast(ml_lds[0][wave][q] - mstar);
#pragma unroll
          for (int nd = 0; nd < 4; ++nd) {
            const int d = nd * 16 + l15;
            float v = o_acc[qg][nd][r] * sc;
            if (w == 0) o_comb[q][d] = v;
            else        o_comb[q][d] += v;
          }
        }
      }
    }
    __syncthreads();
  }

  // ---- final normalize + store ----
  {
    const int q = tid >> 2, dc = (tid & 3) * 16;
    float mstar = fmaxf(fmaxf(ml_lds[0][0][q], ml_lds[0][1][q]),
                        fmaxf(ml_lds[0][2][q], ml_lds[0][3][q]));
    float lstar = ml_lds[1][0][q] * exp2_fast(ml_lds[0][0][q] - mstar)
                + ml_lds[1][1][q] * exp2_fast(ml_lds[0][1][q] - mstar)
                + ml_lds[1][2][q] * exp2_fast(ml_lds[0][2][q] - mstar)
                + ml_lds[1][3][q] * exp2_fast(ml_lds[0][3][q] - mstar);
    const float inv = 1.f / lstar;
    unsigned short* Ob = O + ((size_t)(b * 512 + q0 + q)) * 1024 + h * 64 + dc;
    u16x8 o1, o2;
#pragma unroll
    for (int j = 0; j < 8; ++j) o1[j] = f2bf(o_comb[q][dc + j] * inv);
#pragma unroll
    for (int j = 0; j < 8; ++j) o2[j] = f2bf(o_comb[q][dc + 8 + j] * inv);
    *(u16x8*)(Ob) = o1;
    *(u16x8*)(Ob + 8) = o2;
  }
}

// ---------------------------------------------------------------------------
extern "C" void kernel_launch(void* const* d_in, const int* in_sizes, int n_in,
                              void* d_out, int out_size, void* d_ws, size_t ws_size,
                              hipStream_t stream) {
  const float* x   = (const float*)d_in[0];
  const float* ctx = (const float*)d_in[1];
  const int* mask  = (const int*)d_in[2];
  const float* Wq  = (const float*)d_in[3];
  const float* bq  = (const float*)d_in[4];
  const float* Wk  = (const float*)d_in[5];
  const float* bk  = (const float*)d_in[6];
  const float* Wv  = (const float*)d_in[7];
  const float* bv  = (const float*)d_in[8];
  const float* Wo  = (const float*)d_in[9];
  const float* bo  = (const float*)d_in[10];

  char* ws = (char*)d_ws;
  // [MB offsets] xb 0-4, cb 4-20, w 20-28, qh 28-32, kh 32-48, vh 48-64.
  // Reuse after gemm_qkv: vt 0-16 (over xb+cb head), ah 16-20 (cb tail).
  unsigned short* xb  = (unsigned short*)(ws + ((size_t)0  << 20));
  unsigned short* cb  = (unsigned short*)(ws + ((size_t)4  << 20));
  unsigned short* wqb = (unsigned short*)(ws + ((size_t)20 << 20));
  unsigned short* wkb = (unsigned short*)(ws + ((size_t)22 << 20));
  unsigned short* wvb = (unsigned short*)(ws + ((size_t)24 << 20));
  unsigned short* wob = (unsigned short*)(ws + ((size_t)26 << 20));
  unsigned short* qh  = (unsigned short*)(ws + ((size_t)28 << 20));
  unsigned short* kh  = (unsigned short*)(ws + ((size_t)32 << 20));
  unsigned short* vh  = (unsigned short*)(ws + ((size_t)48 << 20));
  unsigned short* vt  = (unsigned short*)(ws + ((size_t)0  << 20));
  unsigned short* ah  = (unsigned short*)(ws + ((size_t)16 << 20));

  cast_fused<<<14336, 256, 0, stream>>>(x, ctx, Wq, Wk, Wv, Wo,
                                        xb, cb, wqb, wkb, wvb, wob);
  gemm_qkv<<<dim3(64, 18), 256, 0, stream>>>(xb, cb, wqb, wkb, wvb,
                                             bq, bk, bv, qh, kh, vh);
  transpose_v<<<dim3(32, 64), 256, 0, stream>>>(vh, vt);
  attn_kernel<<<dim3(64, 8), 256, 0, stream>>>(qh, kh, vt, mask, ah);
  gemm_o<<<dim3(16, 8), 256, 0, stream>>>(ah, wob, bo, (float*)d_out);
}